// Round 5
// baseline (396.361 us; speedup 1.0000x reference)
//
#include <hip/hip_runtime.h>
#include <hip/hip_bf16.h>

// Problem: B=64, S=1024, H=1024, A=512, E=512
// scores = tanh(encoded@W_enc + b_enc + states@W_dec + b_dec) . w_out (+b_out: softmax-invariant)
// weights = softmax(scores); attention = weights . encoded
// GRU: x=[inputs,attention]; gi=x@W_ih+b_ih; gh=states@W_hh+b_hh; gates -> h_new

typedef __attribute__((ext_vector_type(8))) __bf16 bf16x8;
typedef __attribute__((ext_vector_type(4))) __bf16 bf16x4;
typedef __attribute__((ext_vector_type(4))) float f32x4;

__device__ __forceinline__ float fast_tanh(float x) {
  float xa = fminf(fmaxf(x, -15.f), 15.f);
  float e = __expf(2.f * xa);
  return (e - 1.f) / (e + 1.f);
}

// ---------------- Kernel T: transpose+convert W_enc [1024][512] f32 -> Wt [512][1024] bf16
__global__ __launch_bounds__(256) void wenc_t_kernel(const float* __restrict__ W,
                                                     __bf16* __restrict__ Wt) {
  __shared__ float tile[32][33];
  int k0 = blockIdx.x * 32, a0 = blockIdx.y * 32;
  int tid = threadIdx.x;
  int r = tid >> 3, c4 = (tid & 7) * 4;
  f32x4 v = *(const f32x4*)(W + (long)(k0 + r) * 512 + a0 + c4);
  tile[r][c4 + 0] = v.x; tile[r][c4 + 1] = v.y;
  tile[r][c4 + 2] = v.z; tile[r][c4 + 3] = v.w;
  __syncthreads();
  int a = tid >> 3, k4 = (tid & 7) * 4;
  bf16x4 o = { (__bf16)tile[k4 + 0][a], (__bf16)tile[k4 + 1][a],
               (__bf16)tile[k4 + 2][a], (__bf16)tile[k4 + 3][a] };
  *(bf16x4*)(Wt + (long)(a0 + a) * 1024 + k0 + k4) = o;
}

// ---------------- Kernel A: addv[b][a] = b_enc[a]+b_dec[a]+sum_h states[b,h]*W_dec[h,a]
__global__ __launch_bounds__(256) void dec_proj_kernel(
    const float* __restrict__ states, const float* __restrict__ W_dec,
    const float* __restrict__ b_enc, const float* __restrict__ b_dec,
    float* __restrict__ addv) {
  int b = blockIdx.x, tid = threadIdx.x;
  int a = blockIdx.y * 256 + tid;
  __shared__ float sl[1024];
  for (int i = tid; i < 1024; i += 256) sl[i] = states[b * 1024 + i];
  __syncthreads();
  float c0 = 0.f, c1 = 0.f, c2 = 0.f, c3 = 0.f;
#pragma unroll 4
  for (int i = 0; i < 256; ++i) {
    c0 += sl[i]         * W_dec[(i)        * 512 + a];
    c1 += sl[i + 256]   * W_dec[(i + 256)  * 512 + a];
    c2 += sl[i + 512]   * W_dec[(i + 512)  * 512 + a];
    c3 += sl[i + 768]   * W_dec[(i + 768)  * 512 + a];
  }
  addv[b * 512 + a] = c0 + c1 + c2 + c3 + b_enc[a] + b_dec[a];
}

// ---------------- Kernel B: 256x128 tile, 8 waves, wave = 32 rows (m=2) x 128 cols (n=8).
// A: DIRECT global->register (fp32->bf16 in-reg), no LDS, no per-kstep barriers.
// B: LDS-staged in 256-k chunks (64KB, (col&31)<<4 XOR swizzle), 2 barriers per chunk.
__global__ __launch_bounds__(512, 4) void enc_score_kernel(
    const float* __restrict__ encoded,  // [65536][1024] f32
    const __bf16* __restrict__ Wt,      // [512][1024] bf16 (W_enc^T)
    const float* __restrict__ addv,     // [64][512]
    const float* __restrict__ w_out,    // [512]
    float* __restrict__ psc)            // [4][65536]
{
  __shared__ __attribute__((aligned(16))) char bsm[65536 + 1024];
  float* red = (float*)(bsm + 65536);  // [256]

  const int d = blockIdx.x;
  const int xcd = d & 7;
  const int slot = d >> 3;
  const int bn = slot & 3;
  const int bm = ((slot >> 2) << 3) | xcd;  // 0..255; bn-siblings share bm AND xcd

  const int tid = threadIdx.x;
  const int lane = tid & 63;
  const int wid = tid >> 6;   // 0..7
  const int lr = lane & 15;
  const int lkb = lane >> 4;  // 0..3

  const long row0 = (long)bm * 256;
  const int col0 = bn * 128;

  // A fragment pointers: lane covers rows (wid*32 + lr) and (+16), k-bytes (lkb*32..+32) per kstep
  const float* pa0 = encoded + (row0 + wid * 32 + lr) * 1024 + lkb * 8;
  const float* pa1 = pa0 + 16 * 1024;

  // B staging: thread -> col (tid>>2), k-quarter (tid&3), 8x bf16x8 per chunk
  const int scol = tid >> 2;
  const int skq = tid & 3;
  const __bf16* wtb = Wt + (long)(col0 + scol) * 1024 + skq * 64;
  const int ssw = (scol & 31) << 4;

  // B fragment read: col = n*16+lr; byte = col*512 + (koff ^ ((col&31)<<4))
  // (col&31)<<4 = ((n&1)<<8) | (lr<<4)  (disjoint bits)
  const int rswE = lr << 4;           // even n
  const int rswO = (lr << 4) | 256;   // odd n
  const int bB = lr * 512;

  f32x4 acc[2][8];
#pragma unroll
  for (int m = 0; m < 2; ++m)
#pragma unroll
    for (int n = 0; n < 8; ++n) acc[m][n] = (f32x4){0.f, 0.f, 0.f, 0.f};

  for (int ck = 0; ck < 4; ++ck) {
    if (ck) __syncthreads();  // protect B buffer
#pragma unroll
    for (int j = 0; j < 8; ++j) {
      bf16x8 v = *(const bf16x8*)(wtb + ck * 256 + j * 8);
      *(bf16x8*)(bsm + scol * 512 + ((skq * 128 + j * 16) ^ ssw)) = v;
    }
    __syncthreads();

#pragma unroll
    for (int ktc = 0; ktc < 8; ++ktc) {
      const int kt = ck * 8 + ktc;
      f32x4 x0 = *(const f32x4*)(pa0 + kt * 32);
      f32x4 x1 = *(const f32x4*)(pa0 + kt * 32 + 4);
      f32x4 y0 = *(const f32x4*)(pa1 + kt * 32);
      f32x4 y1 = *(const f32x4*)(pa1 + kt * 32 + 4);
      bf16x8 a0, a1;
#pragma unroll
      for (int i = 0; i < 4; ++i) {
        a0[i] = (__bf16)x0[i]; a0[4 + i] = (__bf16)x1[i];
        a1[i] = (__bf16)y0[i]; a1[4 + i] = (__bf16)y1[i];
      }
      const int kbase = (ktc << 6) | (lkb << 4);
      const int offE = kbase ^ rswE;
      const int offO = kbase ^ rswO;
      __builtin_amdgcn_s_setprio(1);
#pragma unroll
      for (int n = 0; n < 8; ++n) {
        bf16x8 bf_ = *(const bf16x8*)(bsm + bB + n * 8192 + ((n & 1) ? offO : offE));
        acc[0][n] = __builtin_amdgcn_mfma_f32_16x16x32_bf16(a0, bf_, acc[0][n], 0, 0, 0);
        acc[1][n] = __builtin_amdgcn_mfma_f32_16x16x32_bf16(a1, bf_, acc[1][n], 0, 0, 0);
      }
      __builtin_amdgcn_s_setprio(0);
    }
  }

  // Epilogue: per-row sum of tanh(acc + addv[b][col]) * w_out[col]
  // C/D layout: col = lane&15, row = (lane>>4)*4 + reg
  const int b = bm >> 2;  // 256 rows per block, 1024 per batch
  const float* addvb = addv + b * 512;
  float rowsum[2][4];
#pragma unroll
  for (int m = 0; m < 2; ++m)
#pragma unroll
    for (int reg = 0; reg < 4; ++reg) rowsum[m][reg] = 0.f;

#pragma unroll
  for (int n = 0; n < 8; ++n) {
    int col = col0 + n * 16 + lr;
    float av = addvb[col];
    float wo = w_out[col];
#pragma unroll
    for (int m = 0; m < 2; ++m)
#pragma unroll
      for (int reg = 0; reg < 4; ++reg)
        rowsum[m][reg] += fast_tanh(acc[m][n][reg] + av) * wo;
  }
#pragma unroll
  for (int m = 0; m < 2; ++m)
#pragma unroll
    for (int reg = 0; reg < 4; ++reg) {
      float v = rowsum[m][reg];
      v += __shfl_xor(v, 1, 64);
      v += __shfl_xor(v, 2, 64);
      v += __shfl_xor(v, 4, 64);
      v += __shfl_xor(v, 8, 64);
      rowsum[m][reg] = v;
    }
  __syncthreads();  // B buffer reads done; red region is separate but sync before publish
  if (lr == 0) {
#pragma unroll
    for (int m = 0; m < 2; ++m)
#pragma unroll
      for (int reg = 0; reg < 4; ++reg)
        red[wid * 32 + m * 16 + lkb * 4 + reg] = rowsum[m][reg];
  }
  __syncthreads();
  if (tid < 256)
    psc[(long)bn * 65536 + row0 + tid] = red[tid];
}

// ---------------- Kernel C: softmax over S=1024 per batch
__global__ __launch_bounds__(256) void softmax_kernel(const float* __restrict__ psc,
                                                      float* __restrict__ wts) {
  int b = blockIdx.x, tid = threadIdx.x;
  __shared__ float sred[8];
  float sc[4];
  float mx = -1e30f;
#pragma unroll
  for (int i = 0; i < 4; ++i) {
    long r = (long)b * 1024 + tid + i * 256;
    sc[i] = psc[r] + psc[65536 + r] + psc[2 * 65536 + r] + psc[3 * 65536 + r];
    mx = fmaxf(mx, sc[i]);
  }
  for (int off = 1; off < 64; off <<= 1) mx = fmaxf(mx, __shfl_xor(mx, off, 64));
  if ((tid & 63) == 0) sred[tid >> 6] = mx;
  __syncthreads();
  mx = fmaxf(fmaxf(sred[0], sred[1]), fmaxf(sred[2], sred[3]));
  float e[4], sum = 0.f;
#pragma unroll
  for (int i = 0; i < 4; ++i) {
    e[i] = __expf(sc[i] - mx);
    sum += e[i];
  }
  for (int off = 1; off < 64; off <<= 1) sum += __shfl_xor(sum, off, 64);
  if ((tid & 63) == 0) sred[4 + (tid >> 6)] = sum;
  __syncthreads();
  sum = sred[4] + sred[5] + sred[6] + sred[7];
  float inv = 1.f / sum;
#pragma unroll
  for (int i = 0; i < 4; ++i) wts[(long)b * 1024 + tid + i * 256] = e[i] * inv;
}

// ---------------- Kernel D: attention partials over 16 chunks of 64 s (1024 blocks, 4-deep ILP)
__global__ __launch_bounds__(256) void att_part_kernel(const float* __restrict__ encoded,
                                                       const float* __restrict__ wts,
                                                       float* __restrict__ attp) {
  int chunk = blockIdx.x;  // 16
  int b = blockIdx.y;      // 64
  int tid = threadIdx.x;
  f32x4 a0 = (f32x4){0.f, 0.f, 0.f, 0.f};
  f32x4 a1 = a0, a2 = a0, a3 = a0;
  const float* base = encoded + ((long)b * 1024 + chunk * 64) * 1024 + tid * 4;
  const float* w = wts + b * 1024 + chunk * 64;
#pragma unroll 4
  for (int s = 0; s < 64; s += 4) {
    f32x4 v0 = *(const f32x4*)(base + (long)(s + 0) * 1024);
    f32x4 v1 = *(const f32x4*)(base + (long)(s + 1) * 1024);
    f32x4 v2 = *(const f32x4*)(base + (long)(s + 2) * 1024);
    f32x4 v3 = *(const f32x4*)(base + (long)(s + 3) * 1024);
    a0 += v0 * w[s]; a1 += v1 * w[s + 1]; a2 += v2 * w[s + 2]; a3 += v3 * w[s + 3];
  }
  *(f32x4*)(attp + ((long)(b * 16 + chunk)) * 1024 + tid * 4) = (a0 + a1) + (a2 + a3);
}

// ---------------- Kernel E: xcat[b][0:512]=inputs, xcat[b][512:1536]=sum_chunk attp
__global__ __launch_bounds__(256) void xcat_kernel(const float* __restrict__ inputs,
                                                   const float* __restrict__ attp,
                                                   float* __restrict__ xcat) {
  int b = blockIdx.y;
  int k = blockIdx.x * 256 + threadIdx.x;  // 0..1535
  float v;
  if (k < 512) {
    v = inputs[b * 512 + k];
  } else {
    int h = k - 512;
    v = 0.f;
#pragma unroll
    for (int c = 0; c < 16; ++c) v += attp[((long)(b * 16 + c)) * 1024 + h];
  }
  xcat[(long)b * 1536 + k] = v;
}

// ---------------- Kernel F: GRU GEMVs, batch-grouped: chunk-group pinned to one XCD
__global__ __launch_bounds__(512) void gru_gemv_kernel(
    const float* __restrict__ xcat, const float* __restrict__ states,
    const float* __restrict__ W_ih, const float* __restrict__ b_ih,
    const float* __restrict__ W_hh, const float* __restrict__ b_hh,
    float* __restrict__ gi, float* __restrict__ gh) {
  __shared__ float sx[12288];  // 8 batches x 1536 (max)
  const int dd = blockIdx.x;            // 192
  const int xcd = dd & 7;
  const int n = dd >> 3;                // 0..23
  const int cgrp = xcd + 8 * (n >> 3);  // 0..23, pinned to xcd
  const int bg = n & 7;
  const int tid = threadIdx.x;
  const int lcol = tid & 255;
  const int bsel = (tid >> 8) * 4;      // 0 or 4

  if (cgrp < 12) {
    const int col = cgrp * 256 + lcol;
    const float* xb = xcat + (long)bg * 8 * 1536;
    for (int i = tid; i < 3072; i += 512) ((f32x4*)sx)[i] = ((const f32x4*)xb)[i];
    __syncthreads();
    float a0 = b_ih[col], a1 = a0, a2 = a0, a3 = a0;
    const float* x0 = sx + (bsel + 0) * 1536;
    const float* x1 = sx + (bsel + 1) * 1536;
    const float* x2 = sx + (bsel + 2) * 1536;
    const float* x3 = sx + (bsel + 3) * 1536;
    for (int k = 0; k < 1536; k += 4) {
      f32x4 v0 = *(const f32x4*)(x0 + k);
      f32x4 v1 = *(const f32x4*)(x1 + k);
      f32x4 v2 = *(const f32x4*)(x2 + k);
      f32x4 v3 = *(const f32x4*)(x3 + k);
#pragma unroll
      for (int j = 0; j < 4; ++j) {
        float w = W_ih[(long)(k + j) * 3072 + col];
        a0 += v0[j] * w; a1 += v1[j] * w; a2 += v2[j] * w; a3 += v3[j] * w;
      }
    }
    long o = (long)(bg * 8 + bsel) * 3072 + col;
    gi[o] = a0; gi[o + 3072] = a1; gi[o + 6144] = a2; gi[o + 9216] = a3;
  } else {
    const int col = (cgrp - 12) * 256 + lcol;
    const float* sb = states + (long)bg * 8 * 1024;
    for (int i = tid; i < 2048; i += 512) ((f32x4*)sx)[i] = ((const f32x4*)sb)[i];
    __syncthreads();
    float a0 = b_hh[col], a1 = a0, a2 = a0, a3 = a0;
    const float* x0 = sx + (bsel + 0) * 1024;
    const float* x1 = sx + (bsel + 1) * 1024;
    const float* x2 = sx + (bsel + 2) * 1024;
    const float* x3 = sx + (bsel + 3) * 1024;
    for (int k = 0; k < 1024; k += 4) {
      f32x4 v0 = *(const f32x4*)(x0 + k);
      f32x4 v1 = *(const f32x4*)(x1 + k);
      f32x4 v2 = *(const f32x4*)(x2 + k);
      f32x4 v3 = *(const f32x4*)(x3 + k);
#pragma unroll
      for (int j = 0; j < 4; ++j) {
        float w = W_hh[(long)(k + j) * 3072 + col];
        a0 += v0[j] * w; a1 += v1[j] * w; a2 += v2[j] * w; a3 += v3[j] * w;
      }
    }
    long o = (long)(bg * 8 + bsel) * 3072 + col;
    gh[o] = a0; gh[o + 3072] = a1; gh[o + 6144] = a2; gh[o + 9216] = a3;
  }
}

// ---------------- Kernel G: gates
__global__ __launch_bounds__(256) void gate_kernel(const float* __restrict__ gi,
                                                   const float* __restrict__ gh,
                                                   const float* __restrict__ states,
                                                   float* __restrict__ out) {
  int b = blockIdx.y;
  int j = blockIdx.x * 256 + threadIdx.x;  // 0..1023
  long o = (long)b * 3072;
  float ir = gi[o + j], hr = gh[o + j];
  float iz = gi[o + 1024 + j], hz = gh[o + 1024 + j];
  float in_ = gi[o + 2048 + j], hn = gh[o + 2048 + j];
  float r = 1.f / (1.f + __expf(-(ir + hr)));
  float z = 1.f / (1.f + __expf(-(iz + hz)));
  float n = fast_tanh(in_ + r * hn);
  out[(long)b * 1024 + j] = (1.f - z) * n + z * states[(long)b * 1024 + j];
}

extern "C" void kernel_launch(void* const* d_in, const int* in_sizes, int n_in,
                              void* d_out, int out_size, void* d_ws, size_t ws_size,
                              hipStream_t stream) {
  const float* inputs  = (const float*)d_in[0];
  const float* states  = (const float*)d_in[1];
  const float* encoded = (const float*)d_in[2];
  const float* W_enc   = (const float*)d_in[3];
  const float* b_enc   = (const float*)d_in[4];
  const float* W_dec   = (const float*)d_in[5];
  const float* b_dec   = (const float*)d_in[6];
  const float* w_out   = (const float*)d_in[7];
  // d_in[8] = b_out: softmax-invariant, unused
  const float* W_ih    = (const float*)d_in[9];
  const float* b_ih    = (const float*)d_in[10];
  const float* W_hh    = (const float*)d_in[11];
  const float* b_hh    = (const float*)d_in[12];
  float* out = (float*)d_out;
  float* ws = (float*)d_ws;

  float* addv = ws;                 // 32768
  float* psc  = ws + 32768;         // 262144
  float* wts  = ws + 294912;        // 65536
  float* attp = ws + 360448;        // 64*16*1024 = 1048576
  float* xcat = ws + 1409024;       // 98304
  float* gi   = ws + 1507328;       // 196608
  float* gh   = ws + 1703936;       // 196608
  __bf16* Wt  = (__bf16*)(ws + 1900544);  // 512*1024 bf16 (262144 float slots)
  // total 2162688 floats = 8.65 MB

  wenc_t_kernel<<<dim3(32, 16), 256, 0, stream>>>(W_enc, Wt);

  dim3 gA(64, 2);
  dec_proj_kernel<<<gA, 256, 0, stream>>>(states, W_dec, b_enc, b_dec, addv);

  enc_score_kernel<<<1024, 512, 0, stream>>>(encoded, Wt, addv, w_out, psc);

  softmax_kernel<<<64, 256, 0, stream>>>(psc, wts);

  dim3 gD(16, 64);
  att_part_kernel<<<gD, 256, 0, stream>>>(encoded, wts, attp);

  dim3 gE(6, 64);
  xcat_kernel<<<gE, 256, 0, stream>>>(inputs, attp, xcat);

  gru_gemv_kernel<<<192, 512, 0, stream>>>(xcat, states, W_ih, b_ih, W_hh, b_hh, gi, gh);

  dim3 gG(4, 64);
  gate_kernel<<<gG, 256, 0, stream>>>(gi, gh, states, out);
}

// Round 6
// 333.612 us; speedup vs baseline: 1.1881x; 1.1881x over previous
//
#include <hip/hip_runtime.h>
#include <hip/hip_bf16.h>

// Problem: B=64, S=1024, H=1024, A=512, E=512
// scores = tanh(encoded@W_enc + b_enc + states@W_dec + b_dec) . w_out (+b_out: softmax-invariant)
// weights = softmax(scores); attention = weights . encoded
// GRU: x=[inputs,attention]; gi=x@W_ih+b_ih; gh=states@W_hh+b_hh; gates -> h_new

typedef __attribute__((ext_vector_type(8))) __bf16 bf16x8;
typedef __attribute__((ext_vector_type(4))) __bf16 bf16x4;
typedef __attribute__((ext_vector_type(4))) float f32x4;

__device__ __forceinline__ float fast_tanh(float x) {
  float xa = fminf(fmaxf(x, -15.f), 15.f);
  float e = __expf(2.f * xa);
  return (e - 1.f) / (e + 1.f);
}

// global -> LDS direct DMA, 16B per lane. LDS dest must be wave-uniform base;
// HW adds lane*16. Global src is per-lane (pre-swizzled for bank-conflict-free reads).
#define GLOAD16(G, L)                                                              \
  __builtin_amdgcn_global_load_lds(                                                \
      (const __attribute__((address_space(1))) unsigned int*)(const void*)(G),     \
      (__attribute__((address_space(3))) unsigned int*)(void*)(L), 16, 0, 0)

// ---------------- Kernel T: transpose+convert W_enc [1024][512] f32 -> Wt [512][1024] bf16
__global__ __launch_bounds__(256) void wenc_t_kernel(const float* __restrict__ W,
                                                     __bf16* __restrict__ Wt) {
  __shared__ float tile[32][33];
  int k0 = blockIdx.x * 32, a0 = blockIdx.y * 32;
  int tid = threadIdx.x;
  int r = tid >> 3, c4 = (tid & 7) * 4;
  f32x4 v = *(const f32x4*)(W + (long)(k0 + r) * 512 + a0 + c4);
  tile[r][c4 + 0] = v.x; tile[r][c4 + 1] = v.y;
  tile[r][c4 + 2] = v.z; tile[r][c4 + 3] = v.w;
  __syncthreads();
  int a = tid >> 3, k4 = (tid & 7) * 4;
  bf16x4 o = { (__bf16)tile[k4 + 0][a], (__bf16)tile[k4 + 1][a],
               (__bf16)tile[k4 + 2][a], (__bf16)tile[k4 + 3][a] };
  *(bf16x4*)(Wt + (long)(a0 + a) * 1024 + k0 + k4) = o;
}

// ---------------- Kernel A: addv[b][a] = b_enc[a]+b_dec[a]+sum_h states[b,h]*W_dec[h,a]
__global__ __launch_bounds__(256) void dec_proj_kernel(
    const float* __restrict__ states, const float* __restrict__ W_dec,
    const float* __restrict__ b_enc, const float* __restrict__ b_dec,
    float* __restrict__ addv) {
  int b = blockIdx.x, tid = threadIdx.x;
  int a = blockIdx.y * 256 + tid;
  __shared__ float sl[1024];
  for (int i = tid; i < 1024; i += 256) sl[i] = states[b * 1024 + i];
  __syncthreads();
  float c0 = 0.f, c1 = 0.f, c2 = 0.f, c3 = 0.f;
#pragma unroll 4
  for (int i = 0; i < 256; ++i) {
    c0 += sl[i]         * W_dec[(i)        * 512 + a];
    c1 += sl[i + 256]   * W_dec[(i + 256)  * 512 + a];
    c2 += sl[i + 512]   * W_dec[(i + 512)  * 512 + a];
    c3 += sl[i + 768]   * W_dec[(i + 768)  * 512 + a];
  }
  addv[b * 512 + a] = c0 + c1 + c2 + c3 + b_enc[a] + b_dec[a];
}

// ---------------- Kernel B: m97-structure port. 128x128 tile, BK=32, 256 thr / 4 waves (2x2),
// global_load_lds(16B) staging for A (fp32, converted at fragment build) and B (bf16).
// Pre-swizzled global source + linear LDS dest (rule #21): A slot^(row&7), B slot^((col>>1)&3).
// One __syncthreads per K-step (m97 2-phase). LDS: A 2x16KB @0, B 2x8KB @32768, red @49152.
__global__ __launch_bounds__(256, 3) void enc_score_kernel(
    const float* __restrict__ encoded,  // [65536][1024] f32
    const __bf16* __restrict__ Wt,      // [512][1024] bf16 (W_enc^T)
    const float* __restrict__ addv,     // [64][512]
    const float* __restrict__ w_out,    // [512]
    float* __restrict__ psc)            // [4][65536]
{
  __shared__ __attribute__((aligned(16))) char smem[50176];
  float* red = (float*)(smem + 49152);  // [128][2]

  const int d = blockIdx.x;
  const int xcd = d & 7;
  const int slot = d >> 3;
  const int bn = slot & 3;
  const int bm = ((slot >> 2) << 3) | xcd;  // bn-siblings share bm AND xcd

  const int tid = threadIdx.x;
  const int lane = tid & 63;
  const int wid = tid >> 6;   // 0..3
  const int wr = wid >> 1;    // 0..1 (64 rows)
  const int wc = wid & 1;     // 0..1 (64 cols)
  const int lr = lane & 15;
  const int lkb = lane >> 4;  // 0..3

  const long row0 = (long)bm * 128;
  const int col0 = bn * 128;

  // --- staging source addresses (per-lane, pre-swizzled) ---
  // A: LDS[row][slot'] <- G[row][slot' ^ (row&7)]; thread covers row=(tid>>3)+32i, slot'=tid&7
  const int aslot = (tid & 7) ^ ((tid >> 3) & 7);
  const char* gA = (const char*)encoded + (row0 + (tid >> 3)) * 4096 + (aslot << 4);
  // B: LDS[col][slot'] <- G[col][slot' ^ ((col>>1)&3)]; thread covers col=(tid>>2)+64i, slot'=tid&3
  const int bslot = (tid & 3) ^ ((tid >> 3) & 3);
  const char* gB = (const char*)Wt + (long)(col0 + (tid >> 2)) * 2048 + (bslot << 4);
  // LDS wave-uniform bases (HW adds lane*16)
  const int ldsW = wid * 1024;

  // --- fragment read offsets (swizzle phase depends only on lr) ---
  const int aoff0 = ((2 * lkb) ^ (lr & 7)) << 4;
  const int aoff1 = ((2 * lkb + 1) ^ (lr & 7)) << 4;
  const int boff = (lkb ^ ((lr >> 1) & 3)) << 4;
  const int aRowB = (wr * 64 + lr) * 128;  // + m*2048
  const int bColB = (wc * 64 + lr) * 64;   // + n*1024

  f32x4 acc[4][4];
#pragma unroll
  for (int m = 0; m < 4; ++m)
#pragma unroll
    for (int n = 0; n < 4; ++n) acc[m][n] = (f32x4){0.f, 0.f, 0.f, 0.f};

#define STAGE(BUF, KT) do {                                                        \
    _Pragma("unroll") for (int _i = 0; _i < 4; ++_i)                               \
      GLOAD16(gA + (long)_i * 131072 + (KT) * 128,                                 \
              smem + (BUF) * 16384 + _i * 4096 + ldsW);                            \
    _Pragma("unroll") for (int _i = 0; _i < 2; ++_i)                               \
      GLOAD16(gB + (long)_i * 131072 + (KT) * 64,                                  \
              smem + 32768 + (BUF) * 8192 + _i * 4096 + ldsW);                     \
  } while (0)

#define COMPUTE(BUF) do {                                                          \
    const char* _Ab = smem + (BUF) * 16384;                                        \
    const char* _Bb = smem + 32768 + (BUF) * 8192;                                 \
    bf16x8 _af[4], _bv[4];                                                         \
    _Pragma("unroll") for (int _m = 0; _m < 4; ++_m) {                             \
      f32x4 _lo = *(const f32x4*)(_Ab + aRowB + _m * 2048 + aoff0);                \
      f32x4 _hi = *(const f32x4*)(_Ab + aRowB + _m * 2048 + aoff1);                \
      _Pragma("unroll") for (int _j = 0; _j < 4; ++_j) {                           \
        _af[_m][_j] = (__bf16)_lo[_j]; _af[_m][4 + _j] = (__bf16)_hi[_j];          \
      }                                                                            \
    }                                                                              \
    _Pragma("unroll") for (int _n = 0; _n < 4; ++_n)                               \
      _bv[_n] = *(const bf16x8*)(_Bb + bColB + _n * 1024 + boff);                  \
    _Pragma("unroll") for (int _m = 0; _m < 4; ++_m)                               \
      _Pragma("unroll") for (int _n = 0; _n < 4; ++_n)                             \
        acc[_m][_n] =                                                              \
            __builtin_amdgcn_mfma_f32_16x16x32_bf16(_af[_m], _bv[_n], acc[_m][_n], 0, 0, 0); \
  } while (0)

  STAGE(0, 0);
  __syncthreads();
  int buf = 0;
  for (int kt = 0; kt < 32; ++kt) {
    if (kt < 31) STAGE(buf ^ 1, kt + 1);
    COMPUTE(buf);
    __syncthreads();
    buf ^= 1;
  }

#undef STAGE
#undef COMPUTE

  // Epilogue: per-row sum of tanh(acc + addv[b][col]) * w_out[col]
  // C/D layout: col = lane&15, row = (lane>>4)*4 + reg
  const int b = bm >> 3;  // 128 rows per block, 1024 per batch
  const float* addvb = addv + b * 512;
  float rowsum[4][4];
#pragma unroll
  for (int m = 0; m < 4; ++m)
#pragma unroll
    for (int reg = 0; reg < 4; ++reg) rowsum[m][reg] = 0.f;

#pragma unroll
  for (int m = 0; m < 4; ++m) {
#pragma unroll
    for (int n = 0; n < 4; ++n) {
      int col = col0 + wc * 64 + n * 16 + lr;
      float av = addvb[col];
      float wo = w_out[col];
#pragma unroll
      for (int reg = 0; reg < 4; ++reg)
        rowsum[m][reg] += fast_tanh(acc[m][n][reg] + av) * wo;
    }
  }
#pragma unroll
  for (int m = 0; m < 4; ++m)
#pragma unroll
    for (int reg = 0; reg < 4; ++reg) {
      float v = rowsum[m][reg];
      v += __shfl_xor(v, 1, 64);
      v += __shfl_xor(v, 2, 64);
      v += __shfl_xor(v, 4, 64);
      v += __shfl_xor(v, 8, 64);
      rowsum[m][reg] = v;
    }
  if (lr == 0) {
#pragma unroll
    for (int m = 0; m < 4; ++m)
#pragma unroll
      for (int reg = 0; reg < 4; ++reg)
        red[(wr * 64 + m * 16 + lkb * 4 + reg) * 2 + wc] = rowsum[m][reg];
  }
  __syncthreads();
  if (tid < 128)
    psc[(long)bn * 65536 + row0 + tid] = red[tid * 2] + red[tid * 2 + 1];
}

// ---------------- Kernel C: softmax over S=1024 per batch
__global__ __launch_bounds__(256) void softmax_kernel(const float* __restrict__ psc,
                                                      float* __restrict__ wts) {
  int b = blockIdx.x, tid = threadIdx.x;
  __shared__ float sred[8];
  float sc[4];
  float mx = -1e30f;
#pragma unroll
  for (int i = 0; i < 4; ++i) {
    long r = (long)b * 1024 + tid + i * 256;
    sc[i] = psc[r] + psc[65536 + r] + psc[2 * 65536 + r] + psc[3 * 65536 + r];
    mx = fmaxf(mx, sc[i]);
  }
  for (int off = 1; off < 64; off <<= 1) mx = fmaxf(mx, __shfl_xor(mx, off, 64));
  if ((tid & 63) == 0) sred[tid >> 6] = mx;
  __syncthreads();
  mx = fmaxf(fmaxf(sred[0], sred[1]), fmaxf(sred[2], sred[3]));
  float e[4], sum = 0.f;
#pragma unroll
  for (int i = 0; i < 4; ++i) {
    e[i] = __expf(sc[i] - mx);
    sum += e[i];
  }
  for (int off = 1; off < 64; off <<= 1) sum += __shfl_xor(sum, off, 64);
  if ((tid & 63) == 0) sred[4 + (tid >> 6)] = sum;
  __syncthreads();
  sum = sred[4] + sred[5] + sred[6] + sred[7];
  float inv = 1.f / sum;
#pragma unroll
  for (int i = 0; i < 4; ++i) wts[(long)b * 1024 + tid + i * 256] = e[i] * inv;
}

// ---------------- Kernel D: attention partials over 16 chunks of 64 s (1024 blocks, 4-deep ILP)
__global__ __launch_bounds__(256) void att_part_kernel(const float* __restrict__ encoded,
                                                       const float* __restrict__ wts,
                                                       float* __restrict__ attp) {
  int chunk = blockIdx.x;  // 16
  int b = blockIdx.y;      // 64
  int tid = threadIdx.x;
  f32x4 a0 = (f32x4){0.f, 0.f, 0.f, 0.f};
  f32x4 a1 = a0, a2 = a0, a3 = a0;
  const float* base = encoded + ((long)b * 1024 + chunk * 64) * 1024 + tid * 4;
  const float* w = wts + b * 1024 + chunk * 64;
#pragma unroll 4
  for (int s = 0; s < 64; s += 4) {
    f32x4 v0 = *(const f32x4*)(base + (long)(s + 0) * 1024);
    f32x4 v1 = *(const f32x4*)(base + (long)(s + 1) * 1024);
    f32x4 v2 = *(const f32x4*)(base + (long)(s + 2) * 1024);
    f32x4 v3 = *(const f32x4*)(base + (long)(s + 3) * 1024);
    a0 += v0 * w[s]; a1 += v1 * w[s + 1]; a2 += v2 * w[s + 2]; a3 += v3 * w[s + 3];
  }
  *(f32x4*)(attp + ((long)(b * 16 + chunk)) * 1024 + tid * 4) = (a0 + a1) + (a2 + a3);
}

// ---------------- Kernel E: xcat[b][0:512]=inputs, xcat[b][512:1536]=sum_chunk attp
__global__ __launch_bounds__(256) void xcat_kernel(const float* __restrict__ inputs,
                                                   const float* __restrict__ attp,
                                                   float* __restrict__ xcat) {
  int b = blockIdx.y;
  int k = blockIdx.x * 256 + threadIdx.x;  // 0..1535
  float v;
  if (k < 512) {
    v = inputs[b * 512 + k];
  } else {
    int h = k - 512;
    v = 0.f;
#pragma unroll
    for (int c = 0; c < 16; ++c) v += attp[((long)(b * 16 + c)) * 1024 + h];
  }
  xcat[(long)b * 1536 + k] = v;
}

// ---------------- Kernel F: GRU GEMVs, batch-grouped: chunk-group pinned to one XCD
__global__ __launch_bounds__(512) void gru_gemv_kernel(
    const float* __restrict__ xcat, const float* __restrict__ states,
    const float* __restrict__ W_ih, const float* __restrict__ b_ih,
    const float* __restrict__ W_hh, const float* __restrict__ b_hh,
    float* __restrict__ gi, float* __restrict__ gh) {
  __shared__ float sx[12288];  // 8 batches x 1536 (max)
  const int dd = blockIdx.x;            // 192
  const int xcd = dd & 7;
  const int n = dd >> 3;                // 0..23
  const int cgrp = xcd + 8 * (n >> 3);  // 0..23, pinned to xcd
  const int bg = n & 7;
  const int tid = threadIdx.x;
  const int lcol = tid & 255;
  const int bsel = (tid >> 8) * 4;      // 0 or 4

  if (cgrp < 12) {
    const int col = cgrp * 256 + lcol;
    const float* xb = xcat + (long)bg * 8 * 1536;
    for (int i = tid; i < 3072; i += 512) ((f32x4*)sx)[i] = ((const f32x4*)xb)[i];
    __syncthreads();
    float a0 = b_ih[col], a1 = a0, a2 = a0, a3 = a0;
    const float* x0 = sx + (bsel + 0) * 1536;
    const float* x1 = sx + (bsel + 1) * 1536;
    const float* x2 = sx + (bsel + 2) * 1536;
    const float* x3 = sx + (bsel + 3) * 1536;
    for (int k = 0; k < 1536; k += 4) {
      f32x4 v0 = *(const f32x4*)(x0 + k);
      f32x4 v1 = *(const f32x4*)(x1 + k);
      f32x4 v2 = *(const f32x4*)(x2 + k);
      f32x4 v3 = *(const f32x4*)(x3 + k);
#pragma unroll
      for (int j = 0; j < 4; ++j) {
        float w = W_ih[(long)(k + j) * 3072 + col];
        a0 += v0[j] * w; a1 += v1[j] * w; a2 += v2[j] * w; a3 += v3[j] * w;
      }
    }
    long o = (long)(bg * 8 + bsel) * 3072 + col;
    gi[o] = a0; gi[o + 3072] = a1; gi[o + 6144] = a2; gi[o + 9216] = a3;
  } else {
    const int col = (cgrp - 12) * 256 + lcol;
    const float* sb = states + (long)bg * 8 * 1024;
    for (int i = tid; i < 2048; i += 512) ((f32x4*)sx)[i] = ((const f32x4*)sb)[i];
    __syncthreads();
    float a0 = b_hh[col], a1 = a0, a2 = a0, a3 = a0;
    const float* x0 = sx + (bsel + 0) * 1024;
    const float* x1 = sx + (bsel + 1) * 1024;
    const float* x2 = sx + (bsel + 2) * 1024;
    const float* x3 = sx + (bsel + 3) * 1024;
    for (int k = 0; k < 1024; k += 4) {
      f32x4 v0 = *(const f32x4*)(x0 + k);
      f32x4 v1 = *(const f32x4*)(x1 + k);
      f32x4 v2 = *(const f32x4*)(x2 + k);
      f32x4 v3 = *(const f32x4*)(x3 + k);
#pragma unroll
      for (int j = 0; j < 4; ++j) {
        float w = W_hh[(long)(k + j) * 3072 + col];
        a0 += v0[j] * w; a1 += v1[j] * w; a2 += v2[j] * w; a3 += v3[j] * w;
      }
    }
    long o = (long)(bg * 8 + bsel) * 3072 + col;
    gh[o] = a0; gh[o + 3072] = a1; gh[o + 6144] = a2; gh[o + 9216] = a3;
  }
}

// ---------------- Kernel G: gates
__global__ __launch_bounds__(256) void gate_kernel(const float* __restrict__ gi,
                                                   const float* __restrict__ gh,
                                                   const float* __restrict__ states,
                                                   float* __restrict__ out) {
  int b = blockIdx.y;
  int j = blockIdx.x * 256 + threadIdx.x;  // 0..1023
  long o = (long)b * 3072;
  float ir = gi[o + j], hr = gh[o + j];
  float iz = gi[o + 1024 + j], hz = gh[o + 1024 + j];
  float in_ = gi[o + 2048 + j], hn = gh[o + 2048 + j];
  float r = 1.f / (1.f + __expf(-(ir + hr)));
  float z = 1.f / (1.f + __expf(-(iz + hz)));
  float n = fast_tanh(in_ + r * hn);
  out[(long)b * 1024 + j] = (1.f - z) * n + z * states[(long)b * 1024 + j];
}

extern "C" void kernel_launch(void* const* d_in, const int* in_sizes, int n_in,
                              void* d_out, int out_size, void* d_ws, size_t ws_size,
                              hipStream_t stream) {
  const float* inputs  = (const float*)d_in[0];
  const float* states  = (const float*)d_in[1];
  const float* encoded = (const float*)d_in[2];
  const float* W_enc   = (const float*)d_in[3];
  const float* b_enc   = (const float*)d_in[4];
  const float* W_dec   = (const float*)d_in[5];
  const float* b_dec   = (const float*)d_in[6];
  const float* w_out   = (const float*)d_in[7];
  // d_in[8] = b_out: softmax-invariant, unused
  const float* W_ih    = (const float*)d_in[9];
  const float* b_ih    = (const float*)d_in[10];
  const float* W_hh    = (const float*)d_in[11];
  const float* b_hh    = (const float*)d_in[12];
  float* out = (float*)d_out;
  float* ws = (float*)d_ws;

  float* addv = ws;                 // 32768
  float* psc  = ws + 32768;         // 262144
  float* wts  = ws + 294912;        // 65536
  float* attp = ws + 360448;        // 64*16*1024 = 1048576
  float* xcat = ws + 1409024;       // 98304
  float* gi   = ws + 1507328;       // 196608
  float* gh   = ws + 1703936;       // 196608
  __bf16* Wt  = (__bf16*)(ws + 1900544);  // 512*1024 bf16 (262144 float slots)
  // total 2162688 floats = 8.65 MB

  wenc_t_kernel<<<dim3(32, 16), 256, 0, stream>>>(W_enc, Wt);

  dim3 gA(64, 2);
  dec_proj_kernel<<<gA, 256, 0, stream>>>(states, W_dec, b_enc, b_dec, addv);

  enc_score_kernel<<<2048, 256, 0, stream>>>(encoded, Wt, addv, w_out, psc);

  softmax_kernel<<<64, 256, 0, stream>>>(psc, wts);

  dim3 gD(16, 64);
  att_part_kernel<<<gD, 256, 0, stream>>>(encoded, wts, attp);

  dim3 gE(6, 64);
  xcat_kernel<<<gE, 256, 0, stream>>>(inputs, attp, xcat);

  gru_gemv_kernel<<<192, 512, 0, stream>>>(xcat, states, W_ih, b_ih, W_hh, b_hh, gi, gh);

  dim3 gG(4, 64);
  gate_kernel<<<gG, 256, 0, stream>>>(gi, gh, states, out);
}